// Round 7
// baseline (1367.447 us; speedup 1.0000x reference)
//
#include <hip/hip_runtime.h>

// ---------------- LDS-staged GEMM (+bias, optional relu), fp32 VALU ----------------
// out[row][c] = act( sum_k A[row][k] * W[k][c] + bias[c] )
// Block tile: 64 rows x 128 cols. K staged in chunks of 32, BOTH A and W in
// double-buffered LDS (16KB + 32KB = 48KB -> 3 blocks/CU). Inner loop has zero
// global memory ops: 12 ds_read_b128 + 128 FMA per 4-k step.
// T14 split: issue next-chunk global loads (regs) -> compute -> ds_write -> barrier.
template<int K, bool RELU>
__global__ __launch_bounds__(256, 3) void gemm_lds(const float* __restrict__ A,
                                                   const float* __restrict__ W,
                                                   const float* __restrict__ bias,
                                                   float* __restrict__ out, int nrows) {
  constexpr int KC = 32;
  constexpr int NC = K / KC;
  __shared__ float As[2][64 * KC];    // [row][k]  8KB each
  __shared__ float Ws[2][KC * 128];   // [k][col] 16KB each

  const int t = threadIdx.x;
  const int r0 = blockIdx.x * 64;
  const int sr = t >> 3;              // A-staging row 0..31 (and +32)
  const int sk = (t & 7) * 4;         // A-staging k-offset
  const int cg = (t & 31) * 4;        // output col group
  const int rg = (t >> 5) * 8;        // output row group

  int srow0 = r0 + sr;      if (srow0 >= nrows) srow0 = nrows - 1;
  int srow1 = r0 + sr + 32; if (srow1 >= nrows) srow1 = nrows - 1;
  const float* gA0 = A + (size_t)srow0 * K + sk;
  const float* gA1 = A + (size_t)srow1 * K + sk;
  const float4* gW = (const float4*)W;  // chunk c = 1024 float4s at c*1024

  float4 acc[8];
#pragma unroll
  for (int r = 0; r < 8; ++r) acc[r] = make_float4(0.f, 0.f, 0.f, 0.f);

  // prologue: stage chunk 0
  {
    float4 a0 = *(const float4*)(gA0);
    float4 a1 = *(const float4*)(gA1);
    float4 w0 = gW[t], w1 = gW[t + 256], w2 = gW[t + 512], w3 = gW[t + 768];
    *(float4*)&As[0][sr * KC + sk] = a0;
    *(float4*)&As[0][(sr + 32) * KC + sk] = a1;
    float4* wd = (float4*)&Ws[0][0];
    wd[t] = w0; wd[t + 256] = w1; wd[t + 512] = w2; wd[t + 768] = w3;
  }
  __syncthreads();

  for (int c = 0; c < NC; ++c) {
    float4 a0n, a1n, w0n, w1n, w2n, w3n;
    if (c + 1 < NC) {                 // issue next-chunk global loads early
      a0n = *(const float4*)(gA0 + (c + 1) * KC);
      a1n = *(const float4*)(gA1 + (c + 1) * KC);
      const float4* gWc = gW + (size_t)(c + 1) * 1024;
      w0n = gWc[t]; w1n = gWc[t + 256]; w2n = gWc[t + 512]; w3n = gWc[t + 768];
    }
    const float* Asb = As[c & 1];
    const float* Wsb = Ws[c & 1];
#pragma unroll
    for (int kk = 0; kk < KC; kk += 4) {
      float4 w[4];
#pragma unroll
      for (int q = 0; q < 4; ++q)
        w[q] = *(const float4*)&Wsb[(kk + q) * 128 + cg];
#pragma unroll
      for (int r = 0; r < 8; ++r) {
        float4 a = *(const float4*)&Asb[(rg + r) * KC + kk];
        acc[r].x = fmaf(a.x, w[0].x, acc[r].x);
        acc[r].y = fmaf(a.x, w[0].y, acc[r].y);
        acc[r].z = fmaf(a.x, w[0].z, acc[r].z);
        acc[r].w = fmaf(a.x, w[0].w, acc[r].w);
        acc[r].x = fmaf(a.y, w[1].x, acc[r].x);
        acc[r].y = fmaf(a.y, w[1].y, acc[r].y);
        acc[r].z = fmaf(a.y, w[1].z, acc[r].z);
        acc[r].w = fmaf(a.y, w[1].w, acc[r].w);
        acc[r].x = fmaf(a.z, w[2].x, acc[r].x);
        acc[r].y = fmaf(a.z, w[2].y, acc[r].y);
        acc[r].z = fmaf(a.z, w[2].z, acc[r].z);
        acc[r].w = fmaf(a.z, w[2].w, acc[r].w);
        acc[r].x = fmaf(a.w, w[3].x, acc[r].x);
        acc[r].y = fmaf(a.w, w[3].y, acc[r].y);
        acc[r].z = fmaf(a.w, w[3].z, acc[r].z);
        acc[r].w = fmaf(a.w, w[3].w, acc[r].w);
      }
    }
    if (c + 1 < NC) {                 // late LDS writes (vmcnt wait lands here)
      int b = (c + 1) & 1;
      *(float4*)&As[b][sr * KC + sk] = a0n;
      *(float4*)&As[b][(sr + 32) * KC + sk] = a1n;
      float4* wd = (float4*)&Ws[b][0];
      wd[t] = w0n; wd[t + 256] = w1n; wd[t + 512] = w2n; wd[t + 768] = w3n;
    }
    __syncthreads();
  }

  float4 b4 = *(const float4*)(bias + cg);
#pragma unroll
  for (int r = 0; r < 8; ++r) {
    int row = r0 + rg + r;
    if (row < nrows) {
      float4 v = make_float4(acc[r].x + b4.x, acc[r].y + b4.y,
                             acc[r].z + b4.z, acc[r].w + b4.w);
      if (RELU) {
        v.x = fmaxf(v.x, 0.f); v.y = fmaxf(v.y, 0.f);
        v.z = fmaxf(v.z, 0.f); v.w = fmaxf(v.w, 0.f);
      }
      *(float4*)(out + (size_t)row * 128 + cg) = v;
    }
  }
}

// ---------------- CSR build: count -> hierarchical scan -> fill ----------------
__global__ __launch_bounds__(256) void edge_count(const int* __restrict__ ei,
                                                  int* __restrict__ cnt, int E) {
  for (int e = blockIdx.x * 256 + threadIdx.x; e < E; e += gridDim.x * 256)
    atomicAdd(&cnt[ei[E + e]], 1);
}

// K1: per-block (256 counters) sums
__global__ __launch_bounds__(256) void block_sums(const int* __restrict__ cnt,
                                                  int* __restrict__ bsum, int N) {
  __shared__ int s[4];
  int i = blockIdx.x * 256 + threadIdx.x;
  int v = (i < N) ? cnt[i] : 0;
#pragma unroll
  for (int o = 32; o > 0; o >>= 1) v += __shfl_down(v, o, 64);
  if ((threadIdx.x & 63) == 0) s[threadIdx.x >> 6] = v;
  __syncthreads();
  if (threadIdx.x == 0) bsum[blockIdx.x] = s[0] + s[1] + s[2] + s[3];
}

// K2: single small block scans the block sums (nb <= 256), in-place exclusive
__global__ __launch_bounds__(256) void scan_bsum(int* __restrict__ bsum, int nb) {
  __shared__ int s[256];
  int tid = threadIdx.x;
  int v = (tid < nb) ? bsum[tid] : 0;
  s[tid] = v;
  __syncthreads();
#pragma unroll
  for (int o = 1; o < 256; o <<= 1) {
    int tv = (tid >= o) ? s[tid - o] : 0;
    __syncthreads();
    s[tid] += tv;
    __syncthreads();
  }
  if (tid < nb) bsum[tid] = s[tid] - v;
}

// K3: per-block exclusive scan + block offset -> off & cursor
__global__ __launch_bounds__(256) void scan_fin(const int* __restrict__ cnt,
                                               const int* __restrict__ bsum,
                                               int* __restrict__ off,
                                               int* __restrict__ cursor, int N, int E) {
  __shared__ int s[256];
  int tid = threadIdx.x;
  int i = blockIdx.x * 256 + tid;
  int v = (i < N) ? cnt[i] : 0;
  s[tid] = v;
  __syncthreads();
#pragma unroll
  for (int o = 1; o < 256; o <<= 1) {
    int tv = (tid >= o) ? s[tid - o] : 0;
    __syncthreads();
    s[tid] += tv;
    __syncthreads();
  }
  int excl = s[tid] - v + bsum[blockIdx.x];
  if (i < N) { off[i] = excl; cursor[i] = excl; }
  if (i == N - 1) off[N] = E;
}

__global__ __launch_bounds__(256) void edge_fill(const int* __restrict__ ei,
                                                 int* __restrict__ cursor,
                                                 int* __restrict__ perm, int E) {
  for (int e = blockIdx.x * 256 + threadIdx.x; e < E; e += gridDim.x * 256) {
    int pos = atomicAdd(&cursor[ei[E + e]], 1);
    perm[pos] = e;
  }
}

// ---------------- Gather-accumulate (no atomics) ----------------
// One wave per dst node; lane owns cols {2*lane, 2*lane+1}.
__global__ __launch_bounds__(256) void gather_agg(const float* __restrict__ x,
                                                  const int* __restrict__ ei,
                                                  const float* __restrict__ ew,
                                                  const int* __restrict__ off,
                                                  const int* __restrict__ perm,
                                                  float* __restrict__ agg, int N, int E) {
  const int d = blockIdx.x * 4 + (threadIdx.x >> 6);
  if (d >= N) return;
  const int lane = threadIdx.x & 63;
  const int c0 = lane * 2;

  int j = off[d];
  const int jend = off[d + 1];
  float2 acc = make_float2(0.f, 0.f);

  for (; j + 4 <= jend; j += 4) {
    int e0 = perm[j + 0], e1 = perm[j + 1], e2 = perm[j + 2], e3 = perm[j + 3];
    int s0 = ei[e0], s1 = ei[e1], s2 = ei[e2], s3 = ei[e3];
    float w0 = ew[e0], w1 = ew[e1], w2 = ew[e2], w3 = ew[e3];
    float2 v0 = *(const float2*)(x + (size_t)s0 * 128 + c0);
    float2 v1 = *(const float2*)(x + (size_t)s1 * 128 + c0);
    float2 v2 = *(const float2*)(x + (size_t)s2 * 128 + c0);
    float2 v3 = *(const float2*)(x + (size_t)s3 * 128 + c0);
    acc.x = fmaf(w0, v0.x, acc.x); acc.y = fmaf(w0, v0.y, acc.y);
    acc.x = fmaf(w1, v1.x, acc.x); acc.y = fmaf(w1, v1.y, acc.y);
    acc.x = fmaf(w2, v2.x, acc.x); acc.y = fmaf(w2, v2.y, acc.y);
    acc.x = fmaf(w3, v3.x, acc.x); acc.y = fmaf(w3, v3.y, acc.y);
  }
  for (; j < jend; ++j) {
    int e = perm[j];
    int s = ei[e];
    float w = ew[e];
    float2 v = *(const float2*)(x + (size_t)s * 128 + c0);
    acc.x = fmaf(w, v.x, acc.x); acc.y = fmaf(w, v.y, acc.y);
  }
  *(float2*)(agg + (size_t)d * 128 + c0) = acc;
}

extern "C" void kernel_launch(void* const* d_in, const int* in_sizes, int n_in,
                              void* d_out, int out_size, void* d_ws, size_t ws_size,
                              hipStream_t stream) {
  const float* features = (const float*)d_in[0];
  const int* ei = (const int*)d_in[1];   // [2, E] int32
  const float* ew = (const float*)d_in[2];
  const float* Wp = (const float*)d_in[3];
  const float* bp = (const float*)d_in[4];
  const float* Wa = (const float*)d_in[5];
  const float* ba = (const float*)d_in[6];

  const int N = in_sizes[0] / 256;  // 50000
  const int E = in_sizes[1] / 2;    // 800000

  float* out = (float*)d_out;
  float* x   = out;                 // [N,128] scratch lives in d_out until GEMM2

  // Workspace layout (256B-aligned) — identical to R3 (known-fitting):
  char* ws = (char*)d_ws;
  float* agg   = (float*)ws;                                   // N*128 f32 = 25.6 MB
  size_t o = (size_t)N * 128 * sizeof(float);
  o = (o + 255) & ~(size_t)255;
  int* cnt     = (int*)(ws + o); o += (size_t)N * 4;
  o = (o + 255) & ~(size_t)255;
  int* off     = (int*)(ws + o); o += (size_t)(N + 1) * 4;
  o = (o + 255) & ~(size_t)255;
  int* cursor  = (int*)(ws + o); o += (size_t)N * 4;
  o = (o + 255) & ~(size_t)255;
  int* bsum    = (int*)(ws + o); o += (size_t)256 * 4;
  o = (o + 255) & ~(size_t)255;
  int* perm    = (int*)(ws + o); o += (size_t)E * 4;

  const int nb = (N + 255) / 256;   // 196 scan blocks

  // counters must be zeroed every call (ws never re-poisoned between replays).
  hipMemsetAsync(cnt, 0, (size_t)N * sizeof(int), stream);

  // 1) x = features @ W_proj + b_proj
  gemm_lds<256, false><<<(N + 63) / 64, 256, 0, stream>>>(features, Wp, bp, x, N);

  // 2) CSR build by dst (count -> hierarchical scan -> fill)
  edge_count<<<1024, 256, 0, stream>>>(ei, cnt, E);
  block_sums<<<nb, 256, 0, stream>>>(cnt, bsum, N);
  scan_bsum<<<1, 256, 0, stream>>>(bsum, nb);
  scan_fin<<<nb, 256, 0, stream>>>(cnt, bsum, off, cursor, N, E);
  edge_fill<<<1024, 256, 0, stream>>>(ei, cursor, perm, E);

  // 3) agg[d] = sum_{e: dst=d} w_e * x[src_e]   (register accumulate, no atomics)
  gather_agg<<<(N + 3) / 4, 256, 0, stream>>>(x, ei, ew, off, perm, agg, N, E);

  // 4) out = relu(agg @ W_agg + b_agg)   (overwrites the x scratch)
  gemm_lds<128, true><<<(N + 63) / 64, 256, 0, stream>>>(agg, Wa, ba, out, N);
}

// Round 8
// 283.989 us; speedup vs baseline: 4.8151x; 4.8151x over previous
//
#include <hip/hip_runtime.h>

// Async global->LDS DMA, 16B per lane. Dest must be linear in lane order
// (wave-uniform base + lane*16); our staging maps are exactly that.
__device__ __forceinline__ void gll16(const float* g, float* l) {
  __builtin_amdgcn_global_load_lds((const __attribute__((address_space(1))) void*)g,
                                   (__attribute__((address_space(3))) void*)l, 16, 0, 0);
}

// ---------------- LDS-staged GEMM (+bias, optional relu), fp32 VALU ----------------
// out[row][c] = act( sum_k A[row][k] * W[k][c] + bias[c] )
// Block tile: 64 rows x 128 cols. K in chunks of 32; A and W double-buffered in
// LDS (48KB -> 3 blocks/CU, LDS-limited). Staging via global_load_lds (no VGPR
// round-trip, no spill). Inner loop: 12 ds_read_b128 + 128 FMA per 4-k step.
template<int K, bool RELU>
__global__ __launch_bounds__(256) void gemm_lds(const float* __restrict__ A,
                                                const float* __restrict__ W,
                                                const float* __restrict__ bias,
                                                float* __restrict__ out, int nrows) {
  constexpr int KC = 32;
  constexpr int NC = K / KC;
  __shared__ float As[2][64 * KC];    // [row][k]  8KB each; float idx 4*t per thread
  __shared__ float Ws[2][KC * 128];   // [k][col] 16KB each; float idx 4*t + q*1024

  const int t = threadIdx.x;
  const int r0 = blockIdx.x * 64;
  const int sr = t >> 3;              // A-staging row 0..31 (and +32)
  const int sk = (t & 7) * 4;         // A-staging k-offset
  const int cg = (t & 31) * 4;        // output col group
  const int rg = (t >> 5) * 8;        // output row group

  int srow0 = r0 + sr;      if (srow0 >= nrows) srow0 = nrows - 1;
  int srow1 = r0 + sr + 32; if (srow1 >= nrows) srow1 = nrows - 1;
  const float* gA0 = A + (size_t)srow0 * K + sk;   // per-lane global src (ok)
  const float* gA1 = A + (size_t)srow1 * K + sk;

  float4 acc[8];
#pragma unroll
  for (int r = 0; r < 8; ++r) acc[r] = make_float4(0.f, 0.f, 0.f, 0.f);

  // prologue: stage chunk 0 into buffer 0
  {
    float* dA = (float*)&As[0][0];
    float* dW = (float*)&Ws[0][0];
    const float* gWc = W;                       // chunk 0
    gll16(gA0, dA + t * 4);
    gll16(gA1, dA + 1024 + t * 4);
    gll16(gWc + t * 4,        dW + t * 4);
    gll16(gWc + 1024 + t * 4, dW + 1024 + t * 4);
    gll16(gWc + 2048 + t * 4, dW + 2048 + t * 4);
    gll16(gWc + 3072 + t * 4, dW + 3072 + t * 4);
  }
  asm volatile("s_waitcnt vmcnt(0)" ::: "memory");
  __syncthreads();

  for (int c = 0; c < NC; ++c) {
    if (c + 1 < NC) {                 // async prefetch next chunk into other buffer
      int b = (c + 1) & 1;
      float* dA = (float*)&As[b][0];
      float* dW = (float*)&Ws[b][0];
      const float* gWc = W + (size_t)(c + 1) * KC * 128;
      gll16(gA0 + (c + 1) * KC, dA + t * 4);
      gll16(gA1 + (c + 1) * KC, dA + 1024 + t * 4);
      gll16(gWc + t * 4,        dW + t * 4);
      gll16(gWc + 1024 + t * 4, dW + 1024 + t * 4);
      gll16(gWc + 2048 + t * 4, dW + 2048 + t * 4);
      gll16(gWc + 3072 + t * 4, dW + 3072 + t * 4);
    }
    const float* Asb = As[c & 1];
    const float* Wsb = Ws[c & 1];
#pragma unroll
    for (int kk = 0; kk < KC; kk += 4) {
      float4 w[4];
#pragma unroll
      for (int q = 0; q < 4; ++q)
        w[q] = *(const float4*)&Wsb[(kk + q) * 128 + cg];
#pragma unroll
      for (int r = 0; r < 8; ++r) {
        float4 a = *(const float4*)&Asb[(rg + r) * KC + kk];
        acc[r].x = fmaf(a.x, w[0].x, acc[r].x);
        acc[r].y = fmaf(a.x, w[0].y, acc[r].y);
        acc[r].z = fmaf(a.x, w[0].z, acc[r].z);
        acc[r].w = fmaf(a.x, w[0].w, acc[r].w);
        acc[r].x = fmaf(a.y, w[1].x, acc[r].x);
        acc[r].y = fmaf(a.y, w[1].y, acc[r].y);
        acc[r].z = fmaf(a.y, w[1].z, acc[r].z);
        acc[r].w = fmaf(a.y, w[1].w, acc[r].w);
        acc[r].x = fmaf(a.z, w[2].x, acc[r].x);
        acc[r].y = fmaf(a.z, w[2].y, acc[r].y);
        acc[r].z = fmaf(a.z, w[2].z, acc[r].z);
        acc[r].w = fmaf(a.z, w[2].w, acc[r].w);
        acc[r].x = fmaf(a.w, w[3].x, acc[r].x);
        acc[r].y = fmaf(a.w, w[3].y, acc[r].y);
        acc[r].z = fmaf(a.w, w[3].z, acc[r].z);
        acc[r].w = fmaf(a.w, w[3].w, acc[r].w);
      }
    }
    __syncthreads();   // implicit vmcnt(0)+lgkmcnt(0): staged chunk c+1 is ready
  }

  float4 b4 = *(const float4*)(bias + cg);
#pragma unroll
  for (int r = 0; r < 8; ++r) {
    int row = r0 + rg + r;
    if (row < nrows) {
      float4 v = make_float4(acc[r].x + b4.x, acc[r].y + b4.y,
                             acc[r].z + b4.z, acc[r].w + b4.w);
      if (RELU) {
        v.x = fmaxf(v.x, 0.f); v.y = fmaxf(v.y, 0.f);
        v.z = fmaxf(v.z, 0.f); v.w = fmaxf(v.w, 0.f);
      }
      *(float4*)(out + (size_t)row * 128 + cg) = v;
    }
  }
}

// ---------------- CSR build: count -> hierarchical scan -> fill ----------------
__global__ __launch_bounds__(256) void edge_count(const int* __restrict__ ei,
                                                  int* __restrict__ cnt, int E) {
  for (int e = blockIdx.x * 256 + threadIdx.x; e < E; e += gridDim.x * 256)
    atomicAdd(&cnt[ei[E + e]], 1);
}

// K1: per-block (256 counters) sums
__global__ __launch_bounds__(256) void block_sums(const int* __restrict__ cnt,
                                                  int* __restrict__ bsum, int N) {
  __shared__ int s[4];
  int i = blockIdx.x * 256 + threadIdx.x;
  int v = (i < N) ? cnt[i] : 0;
#pragma unroll
  for (int o = 32; o > 0; o >>= 1) v += __shfl_down(v, o, 64);
  if ((threadIdx.x & 63) == 0) s[threadIdx.x >> 6] = v;
  __syncthreads();
  if (threadIdx.x == 0) bsum[blockIdx.x] = s[0] + s[1] + s[2] + s[3];
}

// K2: single small block scans the block sums (nb <= 256), in-place exclusive
__global__ __launch_bounds__(256) void scan_bsum(int* __restrict__ bsum, int nb) {
  __shared__ int s[256];
  int tid = threadIdx.x;
  int v = (tid < nb) ? bsum[tid] : 0;
  s[tid] = v;
  __syncthreads();
#pragma unroll
  for (int o = 1; o < 256; o <<= 1) {
    int tv = (tid >= o) ? s[tid - o] : 0;
    __syncthreads();
    s[tid] += tv;
    __syncthreads();
  }
  if (tid < nb) bsum[tid] = s[tid] - v;
}

// K3: per-block exclusive scan + block offset -> off & cursor
__global__ __launch_bounds__(256) void scan_fin(const int* __restrict__ cnt,
                                               const int* __restrict__ bsum,
                                               int* __restrict__ off,
                                               int* __restrict__ cursor, int N, int E) {
  __shared__ int s[256];
  int tid = threadIdx.x;
  int i = blockIdx.x * 256 + tid;
  int v = (i < N) ? cnt[i] : 0;
  s[tid] = v;
  __syncthreads();
#pragma unroll
  for (int o = 1; o < 256; o <<= 1) {
    int tv = (tid >= o) ? s[tid - o] : 0;
    __syncthreads();
    s[tid] += tv;
    __syncthreads();
  }
  int excl = s[tid] - v + bsum[blockIdx.x];
  if (i < N) { off[i] = excl; cursor[i] = excl; }
  if (i == N - 1) off[N] = E;
}

__global__ __launch_bounds__(256) void edge_fill(const int* __restrict__ ei,
                                                 int* __restrict__ cursor,
                                                 int* __restrict__ perm, int E) {
  for (int e = blockIdx.x * 256 + threadIdx.x; e < E; e += gridDim.x * 256) {
    int pos = atomicAdd(&cursor[ei[E + e]], 1);
    perm[pos] = e;
  }
}

// ---------------- Gather-accumulate (no atomics) ----------------
// One wave per dst node; lane owns cols {2*lane, 2*lane+1}.
__global__ __launch_bounds__(256) void gather_agg(const float* __restrict__ x,
                                                  const int* __restrict__ ei,
                                                  const float* __restrict__ ew,
                                                  const int* __restrict__ off,
                                                  const int* __restrict__ perm,
                                                  float* __restrict__ agg, int N, int E) {
  const int d = blockIdx.x * 4 + (threadIdx.x >> 6);
  if (d >= N) return;
  const int lane = threadIdx.x & 63;
  const int c0 = lane * 2;

  int j = off[d];
  const int jend = off[d + 1];
  float2 acc = make_float2(0.f, 0.f);

  for (; j + 4 <= jend; j += 4) {
    int e0 = perm[j + 0], e1 = perm[j + 1], e2 = perm[j + 2], e3 = perm[j + 3];
    int s0 = ei[e0], s1 = ei[e1], s2 = ei[e2], s3 = ei[e3];
    float w0 = ew[e0], w1 = ew[e1], w2 = ew[e2], w3 = ew[e3];
    float2 v0 = *(const float2*)(x + (size_t)s0 * 128 + c0);
    float2 v1 = *(const float2*)(x + (size_t)s1 * 128 + c0);
    float2 v2 = *(const float2*)(x + (size_t)s2 * 128 + c0);
    float2 v3 = *(const float2*)(x + (size_t)s3 * 128 + c0);
    acc.x = fmaf(w0, v0.x, acc.x); acc.y = fmaf(w0, v0.y, acc.y);
    acc.x = fmaf(w1, v1.x, acc.x); acc.y = fmaf(w1, v1.y, acc.y);
    acc.x = fmaf(w2, v2.x, acc.x); acc.y = fmaf(w2, v2.y, acc.y);
    acc.x = fmaf(w3, v3.x, acc.x); acc.y = fmaf(w3, v3.y, acc.y);
  }
  for (; j < jend; ++j) {
    int e = perm[j];
    int s = ei[e];
    float w = ew[e];
    float2 v = *(const float2*)(x + (size_t)s * 128 + c0);
    acc.x = fmaf(w, v.x, acc.x); acc.y = fmaf(w, v.y, acc.y);
  }
  *(float2*)(agg + (size_t)d * 128 + c0) = acc;
}

extern "C" void kernel_launch(void* const* d_in, const int* in_sizes, int n_in,
                              void* d_out, int out_size, void* d_ws, size_t ws_size,
                              hipStream_t stream) {
  const float* features = (const float*)d_in[0];
  const int* ei = (const int*)d_in[1];   // [2, E] int32
  const float* ew = (const float*)d_in[2];
  const float* Wp = (const float*)d_in[3];
  const float* bp = (const float*)d_in[4];
  const float* Wa = (const float*)d_in[5];
  const float* ba = (const float*)d_in[6];

  const int N = in_sizes[0] / 256;  // 50000
  const int E = in_sizes[1] / 2;    // 800000

  float* out = (float*)d_out;
  float* x   = out;                 // [N,128] scratch lives in d_out until GEMM2

  // Workspace layout (256B-aligned) — identical to R3 (known-fitting):
  char* ws = (char*)d_ws;
  float* agg   = (float*)ws;                                   // N*128 f32 = 25.6 MB
  size_t o = (size_t)N * 128 * sizeof(float);
  o = (o + 255) & ~(size_t)255;
  int* cnt     = (int*)(ws + o); o += (size_t)N * 4;
  o = (o + 255) & ~(size_t)255;
  int* off     = (int*)(ws + o); o += (size_t)(N + 1) * 4;
  o = (o + 255) & ~(size_t)255;
  int* cursor  = (int*)(ws + o); o += (size_t)N * 4;
  o = (o + 255) & ~(size_t)255;
  int* bsum    = (int*)(ws + o); o += (size_t)256 * 4;
  o = (o + 255) & ~(size_t)255;
  int* perm    = (int*)(ws + o); o += (size_t)E * 4;

  const int nb = (N + 255) / 256;   // 196 scan blocks

  // counters must be zeroed every call (ws never re-poisoned between replays).
  hipMemsetAsync(cnt, 0, (size_t)N * sizeof(int), stream);

  // 1) x = features @ W_proj + b_proj
  gemm_lds<256, false><<<(N + 63) / 64, 256, 0, stream>>>(features, Wp, bp, x, N);

  // 2) CSR build by dst (count -> hierarchical scan -> fill)
  edge_count<<<1024, 256, 0, stream>>>(ei, cnt, E);
  block_sums<<<nb, 256, 0, stream>>>(cnt, bsum, N);
  scan_bsum<<<1, 256, 0, stream>>>(bsum, nb);
  scan_fin<<<nb, 256, 0, stream>>>(cnt, bsum, off, cursor, N, E);
  edge_fill<<<1024, 256, 0, stream>>>(ei, cursor, perm, E);

  // 3) agg[d] = sum_{e: dst=d} w_e * x[src_e]   (register accumulate, no atomics)
  gather_agg<<<(N + 3) / 4, 256, 0, stream>>>(x, ei, ew, off, perm, agg, N, E);

  // 4) out = relu(agg @ W_agg + b_agg)   (overwrites the x scratch)
  gemm_lds<128, true><<<(N + 63) / 64, 256, 0, stream>>>(agg, Wa, ba, out, N);
}

// Round 9
// 243.637 us; speedup vs baseline: 5.6127x; 1.1656x over previous
//
#include <hip/hip_runtime.h>

// Async global->LDS DMA, 16B per lane. Dest must be linear in lane order
// (wave-uniform base + lane*16); our staging maps are exactly that.
__device__ __forceinline__ void gll16(const float* g, float* l) {
  __builtin_amdgcn_global_load_lds((const __attribute__((address_space(1))) void*)g,
                                   (__attribute__((address_space(3))) void*)l, 16, 0, 0);
}

// fp32 -> bf16 with round-to-nearest-even (bit-level, no header dependence)
__device__ __forceinline__ unsigned short f2bf(float f) {
  unsigned int u = __float_as_uint(f);
  return (unsigned short)((u + 0x7FFFu + ((u >> 16) & 1u)) >> 16);
}

// ---------------- LDS-staged GEMM (+bias, optional relu), fp32 VALU ----------------
// out[row][c] = act( sum_k A[row][k] * W[k][c] + bias[c] )
// Block tile: 64 rows x 128 cols. K in chunks of 32; A and W double-buffered in
// LDS (48KB -> 3 blocks/CU). Staging via global_load_lds (no VGPR round-trip).
// OBF16: write output as bf16 (RNE) instead of fp32.
template<int K, bool RELU, bool OBF16>
__global__ __launch_bounds__(256) void gemm_lds(const float* __restrict__ A,
                                                const float* __restrict__ W,
                                                const float* __restrict__ bias,
                                                void* __restrict__ outv, int nrows) {
  constexpr int KC = 32;
  constexpr int NC = K / KC;
  __shared__ float As[2][64 * KC];    // [row][k]  8KB each
  __shared__ float Ws[2][KC * 128];   // [k][col] 16KB each

  const int t = threadIdx.x;
  const int r0 = blockIdx.x * 64;
  const int sr = t >> 3;              // A-staging row 0..31 (and +32)
  const int sk = (t & 7) * 4;         // A-staging k-offset
  const int cg = (t & 31) * 4;        // output col group
  const int rg = (t >> 5) * 8;        // output row group

  int srow0 = r0 + sr;      if (srow0 >= nrows) srow0 = nrows - 1;
  int srow1 = r0 + sr + 32; if (srow1 >= nrows) srow1 = nrows - 1;
  const float* gA0 = A + (size_t)srow0 * K + sk;
  const float* gA1 = A + (size_t)srow1 * K + sk;

  float4 acc[8];
#pragma unroll
  for (int r = 0; r < 8; ++r) acc[r] = make_float4(0.f, 0.f, 0.f, 0.f);

  // prologue: stage chunk 0 into buffer 0
  {
    float* dA = (float*)&As[0][0];
    float* dW = (float*)&Ws[0][0];
    const float* gWc = W;
    gll16(gA0, dA + t * 4);
    gll16(gA1, dA + 1024 + t * 4);
    gll16(gWc + t * 4,        dW + t * 4);
    gll16(gWc + 1024 + t * 4, dW + 1024 + t * 4);
    gll16(gWc + 2048 + t * 4, dW + 2048 + t * 4);
    gll16(gWc + 3072 + t * 4, dW + 3072 + t * 4);
  }
  asm volatile("s_waitcnt vmcnt(0)" ::: "memory");
  __syncthreads();

  for (int c = 0; c < NC; ++c) {
    if (c + 1 < NC) {                 // async prefetch next chunk into other buffer
      int b = (c + 1) & 1;
      float* dA = (float*)&As[b][0];
      float* dW = (float*)&Ws[b][0];
      const float* gWc = W + (size_t)(c + 1) * KC * 128;
      gll16(gA0 + (c + 1) * KC, dA + t * 4);
      gll16(gA1 + (c + 1) * KC, dA + 1024 + t * 4);
      gll16(gWc + t * 4,        dW + t * 4);
      gll16(gWc + 1024 + t * 4, dW + 1024 + t * 4);
      gll16(gWc + 2048 + t * 4, dW + 2048 + t * 4);
      gll16(gWc + 3072 + t * 4, dW + 3072 + t * 4);
    }
    const float* Asb = As[c & 1];
    const float* Wsb = Ws[c & 1];
#pragma unroll
    for (int kk = 0; kk < KC; kk += 4) {
      float4 w[4];
#pragma unroll
      for (int q = 0; q < 4; ++q)
        w[q] = *(const float4*)&Wsb[(kk + q) * 128 + cg];
#pragma unroll
      for (int r = 0; r < 8; ++r) {
        float4 a = *(const float4*)&Asb[(rg + r) * KC + kk];
        acc[r].x = fmaf(a.x, w[0].x, acc[r].x);
        acc[r].y = fmaf(a.x, w[0].y, acc[r].y);
        acc[r].z = fmaf(a.x, w[0].z, acc[r].z);
        acc[r].w = fmaf(a.x, w[0].w, acc[r].w);
        acc[r].x = fmaf(a.y, w[1].x, acc[r].x);
        acc[r].y = fmaf(a.y, w[1].y, acc[r].y);
        acc[r].z = fmaf(a.y, w[1].z, acc[r].z);
        acc[r].w = fmaf(a.y, w[1].w, acc[r].w);
        acc[r].x = fmaf(a.z, w[2].x, acc[r].x);
        acc[r].y = fmaf(a.z, w[2].y, acc[r].y);
        acc[r].z = fmaf(a.z, w[2].z, acc[r].z);
        acc[r].w = fmaf(a.z, w[2].w, acc[r].w);
        acc[r].x = fmaf(a.w, w[3].x, acc[r].x);
        acc[r].y = fmaf(a.w, w[3].y, acc[r].y);
        acc[r].z = fmaf(a.w, w[3].z, acc[r].z);
        acc[r].w = fmaf(a.w, w[3].w, acc[r].w);
      }
    }
    __syncthreads();   // implicit vmcnt(0)+lgkmcnt(0): staged chunk c+1 is ready
  }

  float4 b4 = *(const float4*)(bias + cg);
#pragma unroll
  for (int r = 0; r < 8; ++r) {
    int row = r0 + rg + r;
    if (row < nrows) {
      float4 v = make_float4(acc[r].x + b4.x, acc[r].y + b4.y,
                             acc[r].z + b4.z, acc[r].w + b4.w);
      if (RELU) {
        v.x = fmaxf(v.x, 0.f); v.y = fmaxf(v.y, 0.f);
        v.z = fmaxf(v.z, 0.f); v.w = fmaxf(v.w, 0.f);
      }
      if (OBF16) {
        ushort4 u;
        u.x = f2bf(v.x); u.y = f2bf(v.y); u.z = f2bf(v.z); u.w = f2bf(v.w);
        *(ushort4*)((unsigned short*)outv + (size_t)row * 128 + cg) = u;
      } else {
        *(float4*)((float*)outv + (size_t)row * 128 + cg) = v;
      }
    }
  }
}

// ---------------- CSR build: count -> hierarchical scan -> fill ----------------
__global__ __launch_bounds__(256) void edge_count(const int* __restrict__ ei,
                                                  int* __restrict__ cnt, int E) {
  for (int e = blockIdx.x * 256 + threadIdx.x; e < E; e += gridDim.x * 256)
    atomicAdd(&cnt[ei[E + e]], 1);
}

// K1: per-block (256 counters) sums
__global__ __launch_bounds__(256) void block_sums(const int* __restrict__ cnt,
                                                  int* __restrict__ bsum, int N) {
  __shared__ int s[4];
  int i = blockIdx.x * 256 + threadIdx.x;
  int v = (i < N) ? cnt[i] : 0;
#pragma unroll
  for (int o = 32; o > 0; o >>= 1) v += __shfl_down(v, o, 64);
  if ((threadIdx.x & 63) == 0) s[threadIdx.x >> 6] = v;
  __syncthreads();
  if (threadIdx.x == 0) bsum[blockIdx.x] = s[0] + s[1] + s[2] + s[3];
}

// K2: single small block scans the block sums (nb <= 256), in-place exclusive
__global__ __launch_bounds__(256) void scan_bsum(int* __restrict__ bsum, int nb) {
  __shared__ int s[256];
  int tid = threadIdx.x;
  int v = (tid < nb) ? bsum[tid] : 0;
  s[tid] = v;
  __syncthreads();
#pragma unroll
  for (int o = 1; o < 256; o <<= 1) {
    int tv = (tid >= o) ? s[tid - o] : 0;
    __syncthreads();
    s[tid] += tv;
    __syncthreads();
  }
  if (tid < nb) bsum[tid] = s[tid] - v;
}

// K3: per-block exclusive scan + block offset -> off & cursor
__global__ __launch_bounds__(256) void scan_fin(const int* __restrict__ cnt,
                                               const int* __restrict__ bsum,
                                               int* __restrict__ off,
                                               int* __restrict__ cursor, int N, int E) {
  __shared__ int s[256];
  int tid = threadIdx.x;
  int i = blockIdx.x * 256 + tid;
  int v = (i < N) ? cnt[i] : 0;
  s[tid] = v;
  __syncthreads();
#pragma unroll
  for (int o = 1; o < 256; o <<= 1) {
    int tv = (tid >= o) ? s[tid - o] : 0;
    __syncthreads();
    s[tid] += tv;
    __syncthreads();
  }
  int excl = s[tid] - v + bsum[blockIdx.x];
  if (i < N) { off[i] = excl; cursor[i] = excl; }
  if (i == N - 1) off[N] = E;
}

// Fill dst-sorted src-index and weight arrays (gather-side reads become sequential)
__global__ __launch_bounds__(256) void edge_fill2(const int* __restrict__ ei,
                                                  const float* __restrict__ ew,
                                                  int* __restrict__ cursor,
                                                  int* __restrict__ srcs,
                                                  float* __restrict__ wts, int E) {
  for (int e = blockIdx.x * 256 + threadIdx.x; e < E; e += gridDim.x * 256) {
    int pos = atomicAdd(&cursor[ei[E + e]], 1);
    srcs[pos] = ei[e];
    wts[pos] = ew[e];
  }
}

// ---------------- Gather-accumulate from bf16 x (no atomics) ----------------
// One wave per dst node; lane owns cols {2*lane, 2*lane+1} (one uint = 2 bf16).
// Row read = 64 lanes x 4B = 256B coalesced. Accumulate fp32.
__global__ __launch_bounds__(256) void gather_agg_bf(const unsigned short* __restrict__ xb,
                                                     const int* __restrict__ srcs,
                                                     const float* __restrict__ wts,
                                                     const int* __restrict__ off,
                                                     float* __restrict__ agg, int N) {
  const int d = blockIdx.x * 4 + (threadIdx.x >> 6);
  if (d >= N) return;
  const int lane = threadIdx.x & 63;
  const int c0 = lane * 2;

  int j = off[d];
  const int jend = off[d + 1];
  float2 acc = make_float2(0.f, 0.f);

  for (; j + 4 <= jend; j += 4) {
    int s0 = srcs[j], s1 = srcs[j + 1], s2 = srcs[j + 2], s3 = srcs[j + 3];
    float w0 = wts[j], w1 = wts[j + 1], w2 = wts[j + 2], w3 = wts[j + 3];
    unsigned int v0 = *(const unsigned int*)(xb + (size_t)s0 * 128 + c0);
    unsigned int v1 = *(const unsigned int*)(xb + (size_t)s1 * 128 + c0);
    unsigned int v2 = *(const unsigned int*)(xb + (size_t)s2 * 128 + c0);
    unsigned int v3 = *(const unsigned int*)(xb + (size_t)s3 * 128 + c0);
    acc.x = fmaf(w0, __uint_as_float(v0 << 16), acc.x);
    acc.y = fmaf(w0, __uint_as_float(v0 & 0xFFFF0000u), acc.y);
    acc.x = fmaf(w1, __uint_as_float(v1 << 16), acc.x);
    acc.y = fmaf(w1, __uint_as_float(v1 & 0xFFFF0000u), acc.y);
    acc.x = fmaf(w2, __uint_as_float(v2 << 16), acc.x);
    acc.y = fmaf(w2, __uint_as_float(v2 & 0xFFFF0000u), acc.y);
    acc.x = fmaf(w3, __uint_as_float(v3 << 16), acc.x);
    acc.y = fmaf(w3, __uint_as_float(v3 & 0xFFFF0000u), acc.y);
  }
  for (; j < jend; ++j) {
    int s = srcs[j];
    float w = wts[j];
    unsigned int v = *(const unsigned int*)(xb + (size_t)s * 128 + c0);
    acc.x = fmaf(w, __uint_as_float(v << 16), acc.x);
    acc.y = fmaf(w, __uint_as_float(v & 0xFFFF0000u), acc.y);
  }
  *(float2*)(agg + (size_t)d * 128 + c0) = acc;
}

extern "C" void kernel_launch(void* const* d_in, const int* in_sizes, int n_in,
                              void* d_out, int out_size, void* d_ws, size_t ws_size,
                              hipStream_t stream) {
  const float* features = (const float*)d_in[0];
  const int* ei = (const int*)d_in[1];   // [2, E] int32
  const float* ew = (const float*)d_in[2];
  const float* Wp = (const float*)d_in[3];
  const float* bp = (const float*)d_in[4];
  const float* Wa = (const float*)d_in[5];
  const float* ba = (const float*)d_in[6];

  const int N = in_sizes[0] / 256;  // 50000
  const int E = in_sizes[1] / 2;    // 800000

  float* out = (float*)d_out;
  unsigned short* xb = (unsigned short*)d_out;  // bf16 x in d_out (12.8MB of 25.6MB)

  // Workspace layout (256B-aligned):
  char* ws = (char*)d_ws;
  float* agg   = (float*)ws;                                   // N*128 f32 = 25.6 MB
  size_t o = (size_t)N * 128 * sizeof(float);
  o = (o + 255) & ~(size_t)255;
  int* cnt     = (int*)(ws + o); o += (size_t)N * 4;
  o = (o + 255) & ~(size_t)255;
  int* off     = (int*)(ws + o); o += (size_t)(N + 1) * 4;
  o = (o + 255) & ~(size_t)255;
  int* cursor  = (int*)(ws + o); o += (size_t)N * 4;
  o = (o + 255) & ~(size_t)255;
  int* bsum    = (int*)(ws + o); o += (size_t)256 * 4;
  o = (o + 255) & ~(size_t)255;
  int* srcs    = (int*)(ws + o); o += (size_t)E * 4;           // 3.2 MB
  o = (o + 255) & ~(size_t)255;
  float* wts   = (float*)(ws + o); o += (size_t)E * 4;         // 3.2 MB

  const int nb = (N + 255) / 256;   // 196 scan blocks

  // counters must be zeroed every call (ws never re-poisoned between replays).
  hipMemsetAsync(cnt, 0, (size_t)N * sizeof(int), stream);

  // 1) x_bf16 = bf16(features @ W_proj + b_proj)   (into d_out scratch)
  gemm_lds<256, false, true><<<(N + 63) / 64, 256, 0, stream>>>(features, Wp, bp, xb, N);

  // 2) CSR build by dst (count -> hierarchical scan -> fill src/w sorted)
  edge_count<<<1024, 256, 0, stream>>>(ei, cnt, E);
  block_sums<<<nb, 256, 0, stream>>>(cnt, bsum, N);
  scan_bsum<<<1, 256, 0, stream>>>(bsum, nb);
  scan_fin<<<nb, 256, 0, stream>>>(cnt, bsum, off, cursor, N, E);
  edge_fill2<<<1024, 256, 0, stream>>>(ei, ew, cursor, srcs, wts, E);

  // 3) agg[d] = sum_j w_j * x[src_j]   (bf16 gather, fp32 accumulate)
  gather_agg_bf<<<(N + 3) / 4, 256, 0, stream>>>(xb, srcs, wts, off, agg, N);

  // 4) out = relu(agg @ W_agg + b_agg)   (fp32, overwrites x scratch)
  gemm_lds<128, true, false><<<(N + 63) / 64, 256, 0, stream>>>(agg, Wa, ba, out, N);
}

// Round 10
// 213.729 us; speedup vs baseline: 6.3980x; 1.1399x over previous
//
#include <hip/hip_runtime.h>

typedef __attribute__((ext_vector_type(8))) short bf16x8;   // 8 bf16 = 4 VGPRs
typedef __attribute__((ext_vector_type(4))) float f32x4;    // MFMA acc

// fp32 -> bf16 round-to-nearest-even
__device__ __forceinline__ unsigned short f2bf(float f) {
  unsigned int u = __float_as_uint(f);
  return (unsigned short)((u + 0x7FFFu + ((u >> 16) & 1u)) >> 16);
}

// ---------------- MFMA bf16 GEMM: out[M,128] = act(A[M,K] @ W[K,128] + bias) ------
// B passed pre-transposed bf16: BT[128][K]. Block = 4 waves, 64 rows (16/wave).
// Per wave, per 32-k step: 1 A-frag + 8 B-frags + 8 MFMA (16x16x32).
// Fragment layout (m89/m91-verified): A/B lane l -> elem row/col=l&15, k=(l>>4)*8+i;
// C/D lane l -> col=l&15, row=(l>>4)*4+j.
// A_F32: A is fp32, convert to bf16 in-flight. OBF16: write bf16 output.
template<int K, bool RELU, bool OBF16, bool A_F32>
__global__ __launch_bounds__(256) void gemm_mfma(const void* __restrict__ Av,
                                                 const unsigned short* __restrict__ BT,
                                                 const float* __restrict__ bias,
                                                 void* __restrict__ outv, int M) {
  const int t = threadIdx.x;
  const int w = t >> 6;               // wave 0..3
  const int l = t & 63;
  const int r0 = blockIdx.x * 64 + w * 16;
  const int arow = l & 15;
  const int kq = l >> 4;              // 0..3

  int rowA = r0 + arow; if (rowA >= M) rowA = M - 1;   // clamp loads, guard stores

  f32x4 acc[8];
#pragma unroll
  for (int n = 0; n < 8; ++n) acc[n] = (f32x4){0.f, 0.f, 0.f, 0.f};

#pragma unroll
  for (int ks = 0; ks < K / 32; ++ks) {
    bf16x8 a;
    if (A_F32) {
      const float* ap = (const float*)Av + (size_t)rowA * K + ks * 32 + kq * 8;
      float4 f0 = *(const float4*)ap;
      float4 f1 = *(const float4*)(ap + 4);
      a[0] = (short)f2bf(f0.x); a[1] = (short)f2bf(f0.y);
      a[2] = (short)f2bf(f0.z); a[3] = (short)f2bf(f0.w);
      a[4] = (short)f2bf(f1.x); a[5] = (short)f2bf(f1.y);
      a[6] = (short)f2bf(f1.z); a[7] = (short)f2bf(f1.w);
    } else {
      a = *(const bf16x8*)((const unsigned short*)Av + (size_t)rowA * K + ks * 32 + kq * 8);
    }
#pragma unroll
    for (int n = 0; n < 8; ++n) {
      bf16x8 b = *(const bf16x8*)(BT + (size_t)(n * 16 + arow) * K + ks * 32 + kq * 8);
      acc[n] = __builtin_amdgcn_mfma_f32_16x16x32_bf16(a, b, acc[n], 0, 0, 0);
    }
  }

#pragma unroll
  for (int n = 0; n < 8; ++n) {
    int col = n * 16 + arow;          // D col = lane&15
    float bv = bias[col];
#pragma unroll
    for (int j = 0; j < 4; ++j) {
      int row = r0 + kq * 4 + j;      // D row = (lane>>4)*4 + j
      if (row < M) {
        float v = acc[n][j] + bv;
        if (RELU) v = fmaxf(v, 0.f);
        if (OBF16) ((unsigned short*)outv)[(size_t)row * 128 + col] = f2bf(v);
        else       ((float*)outv)[(size_t)row * 128 + col] = v;
      }
    }
  }
}

// ---------------- W transpose + bf16 convert (tiny, once per call) ----------------
// WpT[128][256] <- Wp[256][128];  WaT[128][128] <- Wa[128][128]
__global__ __launch_bounds__(256) void prep_wt(const float* __restrict__ Wp,
                                               const float* __restrict__ Wa,
                                               unsigned short* __restrict__ WpT,
                                               unsigned short* __restrict__ WaT) {
  int i = blockIdx.x * 256 + threadIdx.x;
  if (i < 128 * 256) {                 // WpT: linear write, strided read
    int c = i >> 8, k = i & 255;
    WpT[i] = f2bf(Wp[k * 128 + c]);
  } else if (i < 128 * 256 + 128 * 128) {
    int j = i - 128 * 256;
    int c = j >> 7, k = j & 127;
    WaT[j] = f2bf(Wa[k * 128 + c]);
  }
}

// ---------------- CSR build: count -> hierarchical scan -> fill ----------------
__global__ __launch_bounds__(256) void edge_count(const int* __restrict__ ei,
                                                  int* __restrict__ cnt, int E) {
  for (int e = blockIdx.x * 256 + threadIdx.x; e < E; e += gridDim.x * 256)
    atomicAdd(&cnt[ei[E + e]], 1);
}

__global__ __launch_bounds__(256) void block_sums(const int* __restrict__ cnt,
                                                  int* __restrict__ bsum, int N) {
  __shared__ int s[4];
  int i = blockIdx.x * 256 + threadIdx.x;
  int v = (i < N) ? cnt[i] : 0;
#pragma unroll
  for (int o = 32; o > 0; o >>= 1) v += __shfl_down(v, o, 64);
  if ((threadIdx.x & 63) == 0) s[threadIdx.x >> 6] = v;
  __syncthreads();
  if (threadIdx.x == 0) bsum[blockIdx.x] = s[0] + s[1] + s[2] + s[3];
}

__global__ __launch_bounds__(256) void scan_bsum(int* __restrict__ bsum, int nb) {
  __shared__ int s[256];
  int tid = threadIdx.x;
  int v = (tid < nb) ? bsum[tid] : 0;
  s[tid] = v;
  __syncthreads();
#pragma unroll
  for (int o = 1; o < 256; o <<= 1) {
    int tv = (tid >= o) ? s[tid - o] : 0;
    __syncthreads();
    s[tid] += tv;
    __syncthreads();
  }
  if (tid < nb) bsum[tid] = s[tid] - v;
}

__global__ __launch_bounds__(256) void scan_fin(const int* __restrict__ cnt,
                                               const int* __restrict__ bsum,
                                               int* __restrict__ off,
                                               int* __restrict__ cursor, int N, int E) {
  __shared__ int s[256];
  int tid = threadIdx.x;
  int i = blockIdx.x * 256 + tid;
  int v = (i < N) ? cnt[i] : 0;
  s[tid] = v;
  __syncthreads();
#pragma unroll
  for (int o = 1; o < 256; o <<= 1) {
    int tv = (tid >= o) ? s[tid - o] : 0;
    __syncthreads();
    s[tid] += tv;
    __syncthreads();
  }
  int excl = s[tid] - v + bsum[blockIdx.x];
  if (i < N) { off[i] = excl; cursor[i] = excl; }
  if (i == N - 1) off[N] = E;
}

__global__ __launch_bounds__(256) void edge_fill2(const int* __restrict__ ei,
                                                  const float* __restrict__ ew,
                                                  int* __restrict__ cursor,
                                                  int* __restrict__ srcs,
                                                  float* __restrict__ wts, int E) {
  for (int e = blockIdx.x * 256 + threadIdx.x; e < E; e += gridDim.x * 256) {
    int pos = atomicAdd(&cursor[ei[E + e]], 1);
    srcs[pos] = ei[e];
    wts[pos] = ew[e];
  }
}

// ---------------- Gather-accumulate bf16 x -> bf16 agg (no atomics) ----------------
// One wave per dst node; lane owns cols {2*lane, 2*lane+1} (one uint = 2 bf16).
__global__ __launch_bounds__(256) void gather_agg_bf(const unsigned short* __restrict__ xb,
                                                     const int* __restrict__ srcs,
                                                     const float* __restrict__ wts,
                                                     const int* __restrict__ off,
                                                     unsigned short* __restrict__ aggb,
                                                     int N) {
  const int d = blockIdx.x * 4 + (threadIdx.x >> 6);
  if (d >= N) return;
  const int lane = threadIdx.x & 63;
  const int c0 = lane * 2;

  int j = off[d];
  const int jend = off[d + 1];
  float2 acc = make_float2(0.f, 0.f);

  for (; j + 4 <= jend; j += 4) {
    int s0 = srcs[j], s1 = srcs[j + 1], s2 = srcs[j + 2], s3 = srcs[j + 3];
    float w0 = wts[j], w1 = wts[j + 1], w2 = wts[j + 2], w3 = wts[j + 3];
    unsigned int v0 = *(const unsigned int*)(xb + (size_t)s0 * 128 + c0);
    unsigned int v1 = *(const unsigned int*)(xb + (size_t)s1 * 128 + c0);
    unsigned int v2 = *(const unsigned int*)(xb + (size_t)s2 * 128 + c0);
    unsigned int v3 = *(const unsigned int*)(xb + (size_t)s3 * 128 + c0);
    acc.x = fmaf(w0, __uint_as_float(v0 << 16), acc.x);
    acc.y = fmaf(w0, __uint_as_float(v0 & 0xFFFF0000u), acc.y);
    acc.x = fmaf(w1, __uint_as_float(v1 << 16), acc.x);
    acc.y = fmaf(w1, __uint_as_float(v1 & 0xFFFF0000u), acc.y);
    acc.x = fmaf(w2, __uint_as_float(v2 << 16), acc.x);
    acc.y = fmaf(w2, __uint_as_float(v2 & 0xFFFF0000u), acc.y);
    acc.x = fmaf(w3, __uint_as_float(v3 << 16), acc.x);
    acc.y = fmaf(w3, __uint_as_float(v3 & 0xFFFF0000u), acc.y);
  }
  for (; j < jend; ++j) {
    int s = srcs[j];
    float w = wts[j];
    unsigned int v = *(const unsigned int*)(xb + (size_t)s * 128 + c0);
    acc.x = fmaf(w, __uint_as_float(v << 16), acc.x);
    acc.y = fmaf(w, __uint_as_float(v & 0xFFFF0000u), acc.y);
  }
  unsigned int packed = ((unsigned int)f2bf(acc.y) << 16) | (unsigned int)f2bf(acc.x);
  *(unsigned int*)(aggb + (size_t)d * 128 + c0) = packed;
}

extern "C" void kernel_launch(void* const* d_in, const int* in_sizes, int n_in,
                              void* d_out, int out_size, void* d_ws, size_t ws_size,
                              hipStream_t stream) {
  const float* features = (const float*)d_in[0];
  const int* ei = (const int*)d_in[1];   // [2, E] int32
  const float* ew = (const float*)d_in[2];
  const float* Wp = (const float*)d_in[3];
  const float* bp = (const float*)d_in[4];
  const float* Wa = (const float*)d_in[5];
  const float* ba = (const float*)d_in[6];

  const int N = in_sizes[0] / 256;  // 50000
  const int E = in_sizes[1] / 2;    // 800000

  float* out = (float*)d_out;

  // Workspace layout (256B-aligned), ~32.5 MB total (fits: R9 used 32.6 MB):
  char* ws = (char*)d_ws;
  size_t o = 0;
  unsigned short* xb   = (unsigned short*)(ws + o); o += (size_t)N * 128 * 2;  // 12.8 MB
  o = (o + 255) & ~(size_t)255;
  unsigned short* aggb = (unsigned short*)(ws + o); o += (size_t)N * 128 * 2;  // 12.8 MB
  o = (o + 255) & ~(size_t)255;
  int* cnt     = (int*)(ws + o); o += (size_t)N * 4;
  o = (o + 255) & ~(size_t)255;
  int* off     = (int*)(ws + o); o += (size_t)(N + 1) * 4;
  o = (o + 255) & ~(size_t)255;
  int* cursor  = (int*)(ws + o); o += (size_t)N * 4;
  o = (o + 255) & ~(size_t)255;
  int* bsum    = (int*)(ws + o); o += (size_t)256 * 4;
  o = (o + 255) & ~(size_t)255;
  int* srcs    = (int*)(ws + o); o += (size_t)E * 4;           // 3.2 MB
  o = (o + 255) & ~(size_t)255;
  float* wts   = (float*)(ws + o); o += (size_t)E * 4;         // 3.2 MB
  o = (o + 255) & ~(size_t)255;
  unsigned short* WpT = (unsigned short*)(ws + o); o += (size_t)128 * 256 * 2; // 64 KB
  o = (o + 255) & ~(size_t)255;
  unsigned short* WaT = (unsigned short*)(ws + o); o += (size_t)128 * 128 * 2; // 32 KB

  const int nb = (N + 255) / 256;   // 196 scan blocks
  const int gemm_blocks = (N + 63) / 64;

  // counters must be zeroed every call (ws never re-poisoned between replays).
  hipMemsetAsync(cnt, 0, (size_t)N * sizeof(int), stream);

  // 0) W^T bf16 prep (tiny)
  prep_wt<<<(128 * 256 + 128 * 128 + 255) / 256, 256, 0, stream>>>(Wp, Wa, WpT, WaT);

  // 1) xb = bf16(features @ W_proj + b_proj)   (fp32 A converted in-flight)
  gemm_mfma<256, false, true, true><<<gemm_blocks, 256, 0, stream>>>(features, WpT, bp, xb, N);

  // 2) CSR build by dst (count -> hierarchical scan -> fill src/w sorted)
  edge_count<<<1024, 256, 0, stream>>>(ei, cnt, E);
  block_sums<<<nb, 256, 0, stream>>>(cnt, bsum, N);
  scan_bsum<<<1, 256, 0, stream>>>(bsum, nb);
  scan_fin<<<nb, 256, 0, stream>>>(cnt, bsum, off, cursor, N, E);
  edge_fill2<<<1024, 256, 0, stream>>>(ei, ew, cursor, srcs, wts, E);

  // 3) aggb[d] = bf16( sum_j w_j * x[src_j] )   (bf16 gather, fp32 accumulate)
  gather_agg_bf<<<(N + 3) / 4, 256, 0, stream>>>(xb, srcs, wts, off, aggb, N);

  // 4) out = relu(aggb @ W_agg + b_agg)   (bf16 MFMA, fp32 out)
  gemm_mfma<128, true, false, false><<<gemm_blocks, 256, 0, stream>>>(aggb, WaT, ba, out, N);
}

// Round 11
// 206.738 us; speedup vs baseline: 6.6144x; 1.0338x over previous
//
#include <hip/hip_runtime.h>

typedef __attribute__((ext_vector_type(8))) short bf16x8;   // 8 bf16 = 4 VGPRs
typedef __attribute__((ext_vector_type(4))) float f32x4;    // MFMA acc

// fp32 -> bf16 round-to-nearest-even
__device__ __forceinline__ unsigned short f2bf(float f) {
  unsigned int u = __float_as_uint(f);
  return (unsigned short)((u + 0x7FFFu + ((u >> 16) & 1u)) >> 16);
}

// ---------------- MFMA bf16 GEMM: out[M,128] = act(A[M,K] @ W[K,128] + bias) ------
// B passed pre-transposed bf16: BT[128][K]. Block = 4 waves, 64 rows (16/wave).
// Fragment layout (m89/m91-verified): A/B lane l -> elem row/col=l&15, k=(l>>4)*8+i;
// C/D lane l -> col=l&15, row=(l>>4)*4+j.
template<int K, bool RELU, bool OBF16, bool A_F32>
__global__ __launch_bounds__(256) void gemm_mfma(const void* __restrict__ Av,
                                                 const unsigned short* __restrict__ BT,
                                                 const float* __restrict__ bias,
                                                 void* __restrict__ outv, int M) {
  const int t = threadIdx.x;
  const int w = t >> 6;               // wave 0..3
  const int l = t & 63;
  const int r0 = blockIdx.x * 64 + w * 16;
  const int arow = l & 15;
  const int kq = l >> 4;              // 0..3

  int rowA = r0 + arow; if (rowA >= M) rowA = M - 1;   // clamp loads, guard stores

  f32x4 acc[8];
#pragma unroll
  for (int n = 0; n < 8; ++n) acc[n] = (f32x4){0.f, 0.f, 0.f, 0.f};

#pragma unroll
  for (int ks = 0; ks < K / 32; ++ks) {
    bf16x8 a;
    if (A_F32) {
      const float* ap = (const float*)Av + (size_t)rowA * K + ks * 32 + kq * 8;
      float4 f0 = *(const float4*)ap;
      float4 f1 = *(const float4*)(ap + 4);
      a[0] = (short)f2bf(f0.x); a[1] = (short)f2bf(f0.y);
      a[2] = (short)f2bf(f0.z); a[3] = (short)f2bf(f0.w);
      a[4] = (short)f2bf(f1.x); a[5] = (short)f2bf(f1.y);
      a[6] = (short)f2bf(f1.z); a[7] = (short)f2bf(f1.w);
    } else {
      a = *(const bf16x8*)((const unsigned short*)Av + (size_t)rowA * K + ks * 32 + kq * 8);
    }
#pragma unroll
    for (int n = 0; n < 8; ++n) {
      bf16x8 b = *(const bf16x8*)(BT + (size_t)(n * 16 + arow) * K + ks * 32 + kq * 8);
      acc[n] = __builtin_amdgcn_mfma_f32_16x16x32_bf16(a, b, acc[n], 0, 0, 0);
    }
  }

#pragma unroll
  for (int n = 0; n < 8; ++n) {
    int col = n * 16 + arow;          // D col = lane&15
    float bv = bias[col];
#pragma unroll
    for (int j = 0; j < 4; ++j) {
      int row = r0 + kq * 4 + j;      // D row = (lane>>4)*4 + j
      if (row < M) {
        float v = acc[n][j] + bv;
        if (RELU) v = fmaxf(v, 0.f);
        if (OBF16) ((unsigned short*)outv)[(size_t)row * 128 + col] = f2bf(v);
        else       ((float*)outv)[(size_t)row * 128 + col] = v;
      }
    }
  }
}

// ---------------- W transpose + bf16 convert (tiny, once per call) ----------------
__global__ __launch_bounds__(256) void prep_wt(const float* __restrict__ Wp,
                                               const float* __restrict__ Wa,
                                               unsigned short* __restrict__ WpT,
                                               unsigned short* __restrict__ WaT) {
  int i = blockIdx.x * 256 + threadIdx.x;
  if (i < 128 * 256) {                 // WpT[128][256] <- Wp[256][128]
    int c = i >> 8, k = i & 255;
    WpT[i] = f2bf(Wp[k * 128 + c]);
  } else if (i < 128 * 256 + 128 * 128) {
    int j = i - 128 * 256;             // WaT[128][128] <- Wa[128][128]
    int c = j >> 7, k = j & 127;
    WaT[j] = f2bf(Wa[k * 128 + c]);
  }
}

// ---------------- CSR build: count -> hierarchical scan -> fill ----------------
__global__ __launch_bounds__(256) void edge_count(const int* __restrict__ ei,
                                                  int* __restrict__ cnt, int E) {
  for (int e = blockIdx.x * 256 + threadIdx.x; e < E; e += gridDim.x * 256)
    atomicAdd(&cnt[ei[E + e]], 1);
}

__global__ __launch_bounds__(256) void block_sums(const int* __restrict__ cnt,
                                                  int* __restrict__ bsum, int N) {
  __shared__ int s[4];
  int i = blockIdx.x * 256 + threadIdx.x;
  int v = (i < N) ? cnt[i] : 0;
#pragma unroll
  for (int o = 32; o > 0; o >>= 1) v += __shfl_down(v, o, 64);
  if ((threadIdx.x & 63) == 0) s[threadIdx.x >> 6] = v;
  __syncthreads();
  if (threadIdx.x == 0) bsum[blockIdx.x] = s[0] + s[1] + s[2] + s[3];
}

__global__ __launch_bounds__(256) void scan_bsum(int* __restrict__ bsum, int nb) {
  __shared__ int s[256];
  int tid = threadIdx.x;
  int v = (tid < nb) ? bsum[tid] : 0;
  s[tid] = v;
  __syncthreads();
#pragma unroll
  for (int o = 1; o < 256; o <<= 1) {
    int tv = (tid >= o) ? s[tid - o] : 0;
    __syncthreads();
    s[tid] += tv;
    __syncthreads();
  }
  if (tid < nb) bsum[tid] = s[tid] - v;
}

__global__ __launch_bounds__(256) void scan_fin(const int* __restrict__ cnt,
                                               const int* __restrict__ bsum,
                                               int* __restrict__ off,
                                               int* __restrict__ cursor, int N, int E) {
  __shared__ int s[256];
  int tid = threadIdx.x;
  int i = blockIdx.x * 256 + tid;
  int v = (i < N) ? cnt[i] : 0;
  s[tid] = v;
  __syncthreads();
#pragma unroll
  for (int o = 1; o < 256; o <<= 1) {
    int tv = (tid >= o) ? s[tid - o] : 0;
    __syncthreads();
    s[tid] += tv;
    __syncthreads();
  }
  int excl = s[tid] - v + bsum[blockIdx.x];
  if (i < N) { off[i] = excl; cursor[i] = excl; }
  if (i == N - 1) off[N] = E;
}

// Fill dst-sorted packed metadata: meta = (src << 16) | bf16(weight).
// One 4B random store per edge (was 2x 4B to two regions) -> write-amp halves.
__global__ __launch_bounds__(256) void edge_fill3(const int* __restrict__ ei,
                                                  const float* __restrict__ ew,
                                                  int* __restrict__ cursor,
                                                  unsigned int* __restrict__ meta, int E) {
  for (int e = blockIdx.x * 256 + threadIdx.x; e < E; e += gridDim.x * 256) {
    int pos = atomicAdd(&cursor[ei[E + e]], 1);
    meta[pos] = ((unsigned int)ei[e] << 16) | (unsigned int)f2bf(ew[e]);
  }
}

// ---------------- Gather-accumulate bf16 x -> bf16 agg (no atomics) ----------------
// One wave per dst node; lane owns cols {2*lane, 2*lane+1} (one uint = 2 bf16).
__global__ __launch_bounds__(256) void gather_agg_bf(const unsigned short* __restrict__ xb,
                                                     const unsigned int* __restrict__ meta,
                                                     const int* __restrict__ off,
                                                     unsigned short* __restrict__ aggb,
                                                     int N) {
  const int d = blockIdx.x * 4 + (threadIdx.x >> 6);
  if (d >= N) return;
  const int lane = threadIdx.x & 63;
  const int c0 = lane * 2;

  int j = off[d];
  const int jend = off[d + 1];
  float2 acc = make_float2(0.f, 0.f);

  for (; j + 4 <= jend; j += 4) {
    unsigned int m0 = meta[j], m1 = meta[j + 1], m2 = meta[j + 2], m3 = meta[j + 3];
    unsigned int v0 = *(const unsigned int*)(xb + (size_t)(m0 >> 16) * 128 + c0);
    unsigned int v1 = *(const unsigned int*)(xb + (size_t)(m1 >> 16) * 128 + c0);
    unsigned int v2 = *(const unsigned int*)(xb + (size_t)(m2 >> 16) * 128 + c0);
    unsigned int v3 = *(const unsigned int*)(xb + (size_t)(m3 >> 16) * 128 + c0);
    float w0 = __uint_as_float(m0 << 16), w1 = __uint_as_float(m1 << 16);
    float w2 = __uint_as_float(m2 << 16), w3 = __uint_as_float(m3 << 16);
    acc.x = fmaf(w0, __uint_as_float(v0 << 16), acc.x);
    acc.y = fmaf(w0, __uint_as_float(v0 & 0xFFFF0000u), acc.y);
    acc.x = fmaf(w1, __uint_as_float(v1 << 16), acc.x);
    acc.y = fmaf(w1, __uint_as_float(v1 & 0xFFFF0000u), acc.y);
    acc.x = fmaf(w2, __uint_as_float(v2 << 16), acc.x);
    acc.y = fmaf(w2, __uint_as_float(v2 & 0xFFFF0000u), acc.y);
    acc.x = fmaf(w3, __uint_as_float(v3 << 16), acc.x);
    acc.y = fmaf(w3, __uint_as_float(v3 & 0xFFFF0000u), acc.y);
  }
  for (; j < jend; ++j) {
    unsigned int m = meta[j];
    unsigned int v = *(const unsigned int*)(xb + (size_t)(m >> 16) * 128 + c0);
    float w = __uint_as_float(m << 16);
    acc.x = fmaf(w, __uint_as_float(v << 16), acc.x);
    acc.y = fmaf(w, __uint_as_float(v & 0xFFFF0000u), acc.y);
  }
  unsigned int packed = ((unsigned int)f2bf(acc.y) << 16) | (unsigned int)f2bf(acc.x);
  *(unsigned int*)(aggb + (size_t)d * 128 + c0) = packed;
}

extern "C" void kernel_launch(void* const* d_in, const int* in_sizes, int n_in,
                              void* d_out, int out_size, void* d_ws, size_t ws_size,
                              hipStream_t stream) {
  const float* features = (const float*)d_in[0];
  const int* ei = (const int*)d_in[1];   // [2, E] int32
  const float* ew = (const float*)d_in[2];
  const float* Wp = (const float*)d_in[3];
  const float* bp = (const float*)d_in[4];
  const float* Wa = (const float*)d_in[5];
  const float* ba = (const float*)d_in[6];

  const int N = in_sizes[0] / 256;  // 50000
  const int E = in_sizes[1] / 2;    // 800000

  float* out = (float*)d_out;

  // Workspace layout (256B-aligned), ~29.5 MB total:
  char* ws = (char*)d_ws;
  size_t o = 0;
  unsigned short* xb   = (unsigned short*)(ws + o); o += (size_t)N * 128 * 2;  // 12.8 MB
  o = (o + 255) & ~(size_t)255;
  unsigned short* aggb = (unsigned short*)(ws + o); o += (size_t)N * 128 * 2;  // 12.8 MB
  o = (o + 255) & ~(size_t)255;
  int* cnt     = (int*)(ws + o); o += (size_t)N * 4;
  o = (o + 255) & ~(size_t)255;
  int* off     = (int*)(ws + o); o += (size_t)(N + 1) * 4;
  o = (o + 255) & ~(size_t)255;
  int* cursor  = (int*)(ws + o); o += (size_t)N * 4;
  o = (o + 255) & ~(size_t)255;
  int* bsum    = (int*)(ws + o); o += (size_t)256 * 4;
  o = (o + 255) & ~(size_t)255;
  unsigned int* meta = (unsigned int*)(ws + o); o += (size_t)E * 4;            // 3.2 MB
  o = (o + 255) & ~(size_t)255;
  unsigned short* WpT = (unsigned short*)(ws + o); o += (size_t)128 * 256 * 2; // 64 KB
  o = (o + 255) & ~(size_t)255;
  unsigned short* WaT = (unsigned short*)(ws + o); o += (size_t)128 * 128 * 2; // 32 KB

  const int nb = (N + 255) / 256;   // 196 scan blocks
  const int gemm_blocks = (N + 63) / 64;

  // counters must be zeroed every call (ws never re-poisoned between replays).
  hipMemsetAsync(cnt, 0, (size_t)N * sizeof(int), stream);

  // 0) W^T bf16 prep (tiny)
  prep_wt<<<(128 * 256 + 128 * 128 + 255) / 256, 256, 0, stream>>>(Wp, Wa, WpT, WaT);

  // 1) xb = bf16(features @ W_proj + b_proj)   (fp32 A converted in-flight)
  gemm_mfma<256, false, true, true><<<gemm_blocks, 256, 0, stream>>>(features, WpT, bp, xb, N);

  // 2) CSR build by dst (count -> hierarchical scan -> packed fill)
  edge_count<<<1024, 256, 0, stream>>>(ei, cnt, E);
  block_sums<<<nb, 256, 0, stream>>>(cnt, bsum, N);
  scan_bsum<<<1, 256, 0, stream>>>(bsum, nb);
  scan_fin<<<nb, 256, 0, stream>>>(cnt, bsum, off, cursor, N, E);
  edge_fill3<<<1024, 256, 0, stream>>>(ei, ew, cursor, meta, E);

  // 3) aggb[d] = bf16( sum_j w_j * x[src_j] )   (bf16 gather, fp32 accumulate)
  gather_agg_bf<<<(N + 3) / 4, 256, 0, stream>>>(xb, meta, off, aggb, N);

  // 4) out = relu(aggb @ W_agg + b_agg)   (bf16 MFMA, fp32 out)
  gemm_mfma<128, true, false, false><<<gemm_blocks, 256, 0, stream>>>(aggb, WaT, ba, out, N);
}